// Round 14
// baseline (150.900 us; speedup 1.0000x reference)
//
#include <hip/hip_runtime.h>

// SelfAttentionBlock: B=4, C=64, N=4096, fp32 in/out.
// R14: attn waves = 4 i-groups SHARING one j-window (K/V loads 4-way
// identical -> L1 dedup) so occupancy rises without cutting MFMA/load ratio
// (R8/R10's mistake). Per-wave 32i x 64j: ~116 regs -> 3-4 waves/SIMD
// (launch_bounds(256,3) guardrail vs spill). Waves own disjoint i => no
// cross-wave reduction, attn has ZERO LDS. SPLIT=8 keeps 1024 blocks.
// Note: harness fill of d_ws (41us, 268MB @ 6.5TB/s) is fixed overhead.

#define B_ 4
#define C_ 64
#define N_ 4096
#define LDSK 70    // proj LDS stride (bf16)
#define LDSW 18    // proj V-buf stride
#define SPLIT 8
#define MSHIFT 12.0f
#define QSCALE 0.18033688011111773f  // (1/sqrt(64)) * log2(e)

typedef short short8 __attribute__((ext_vector_type(8)));
typedef short bh4 __attribute__((ext_vector_type(4)));
typedef float f32x4 __attribute__((ext_vector_type(4)));

__device__ __forceinline__ short f2bf(float f) {
    __bf16 h = (__bf16)f;
    return __builtin_bit_cast(short, h);
}

__device__ __forceinline__ f32x4 mfma16(short8 a, short8 b, f32x4 c) {
    return __builtin_amdgcn_mfma_f32_16x16x32_bf16(a, b, c, 0, 0, 0);
}

__device__ __forceinline__ short8 loadWfrag(const float* __restrict__ W, int row, int kbase) {
    const float4 f0 = *(const float4*)(W + row * 64 + kbase);
    const float4 f1 = *(const float4*)(W + row * 64 + kbase + 4);
    short8 r;
    r[0] = f2bf(f0.x); r[1] = f2bf(f0.y); r[2] = f2bf(f0.z); r[3] = f2bf(f0.w);
    r[4] = f2bf(f1.x); r[5] = f2bf(f1.y); r[6] = f2bf(f1.z); r[7] = f2bf(f1.w);
    return r;
}

// 1024 blocks: (b, 16-row n-slice). Each wave owns one 16-wide o/c quarter.
// V goes to Vp: within each 32-j group, short position p = hi*8+e holds
// j = (e<4 ? hi*4+e : 16+hi*4+e-4)  -> attn's PV B-frag is one b128.
__global__ __launch_bounds__(256) void proj_kernel(
    const float* __restrict__ x,
    const float* __restrict__ Wq, const float* __restrict__ bq,
    const float* __restrict__ Wk, const float* __restrict__ bk,
    const float* __restrict__ Wv, const float* __restrict__ bv,
    short* __restrict__ Qt, short* __restrict__ Kt, short* __restrict__ Vp)
{
    __shared__ __align__(16) short xT[16 * LDSK];    // [n][c]
    __shared__ __align__(16) short bufQ[16 * LDSK];  // [n][o]
    __shared__ __align__(16) short bufK[16 * LDSK];
    __shared__ __align__(16) short bufV[64 * LDSW];  // [c][n_local]
    const int tid = threadIdx.x;
    const int b  = blockIdx.x >> 8;
    const int n0 = (blockIdx.x & 255) << 4;
    const int w = tid >> 6, lane = tid & 63;
    const int lo = lane & 15, hi = lane >> 4;

    // Stage x^T tile [16n][64c]: thread (c = tid>>2, nq = tid&3) reads float4.
    {
        const int c  = tid >> 2;
        const int nq = tid & 3;
        const float4 v = *(const float4*)(x + ((size_t)(b * C_ + c)) * N_ + n0 + nq * 4);
        xT[(nq * 4 + 0) * LDSK + c] = f2bf(v.x);
        xT[(nq * 4 + 1) * LDSK + c] = f2bf(v.y);
        xT[(nq * 4 + 2) * LDSK + c] = f2bf(v.z);
        xT[(nq * 4 + 3) * LDSK + c] = f2bf(v.w);
    }
    __syncthreads();

    short8 aX[2];
    aX[0] = *(const short8*)&xT[lo * LDSK + 0 * 32 + hi * 8];
    aX[1] = *(const short8*)&xT[lo * LDSK + 1 * 32 + hi * 8];

    // Q,K: D[n][o], o-quarter = w. A = x^T rows, B = W rows (k-contiguous).
    {
        f32x4 acc = {0.f, 0.f, 0.f, 0.f};
        #pragma unroll
        for (int kh = 0; kh < 2; ++kh)
            acc = mfma16(aX[kh], loadWfrag(Wq, w * 16 + lo, kh * 32 + hi * 8), acc);
        const float bs = bq[w * 16 + lo];
        #pragma unroll
        for (int r = 0; r < 4; ++r)
            bufQ[(hi * 4 + r) * LDSK + w * 16 + lo] = f2bf((acc[r] + bs) * QSCALE);
    }
    {
        f32x4 acc = {0.f, 0.f, 0.f, 0.f};
        #pragma unroll
        for (int kh = 0; kh < 2; ++kh)
            acc = mfma16(aX[kh], loadWfrag(Wk, w * 16 + lo, kh * 32 + hi * 8), acc);
        const float bs = bk[w * 16 + lo];
        #pragma unroll
        for (int r = 0; r < 4; ++r)
            bufK[(hi * 4 + r) * LDSK + w * 16 + lo] = f2bf(acc[r] + bs);
    }
    // V: D[o][n], o-quarter = w. A = W rows, B = x^T rows (same frag as aX).
    {
        short8 aV[2];
        aV[0] = loadWfrag(Wv, w * 16 + lo, 0 * 32 + hi * 8);
        aV[1] = loadWfrag(Wv, w * 16 + lo, 1 * 32 + hi * 8);
        f32x4 acc = {0.f, 0.f, 0.f, 0.f};
        #pragma unroll
        for (int kh = 0; kh < 2; ++kh)
            acc = mfma16(aV[kh], aX[kh], acc);
        #pragma unroll
        for (int r = 0; r < 4; ++r) {
            const int o = w * 16 + hi * 4 + r;
            bufV[o * LDSW + lo] = f2bf(acc[r] + bv[o]);
        }
    }
    __syncthreads();

    // Q/K stores: 16x64 shorts contiguous -> 256 threads x 8B.
    {
        const int row = tid >> 4, c4 = (tid & 15) * 4;
        const size_t gbase = ((size_t)(b * N_ + n0 + row)) * 64 + c4;
        *(uint2*)(Qt + gbase) = *(const uint2*)&bufQ[row * LDSK + c4];
        *(uint2*)(Kt + gbase) = *(const uint2*)&bufK[row * LDSK + c4];
    }
    // Vp store: thread (c = tid>>2, p = tid&3) writes n_local p*4..p*4+3.
    {
        const int c = tid >> 2, p = tid & 3;
        const int goff = (n0 & ~31) + p * 8 + ((n0 & 16) ? 4 : 0);
        *(uint2*)(Vp + ((size_t)(b * C_ + c)) * N_ + goff) =
            *(const uint2*)&bufV[c * LDSW + p * 4];
    }
}

__global__ __launch_bounds__(256, 3) void attn_kernel(
    const short* __restrict__ Qt, const short* __restrict__ Kt, const short* __restrict__ Vp,
    float* __restrict__ pO, float* __restrict__ pL)
{
    const int tid = threadIdx.x;
    const int b  = blockIdx.x >> 5;            // 32 i0-tiles per batch
    const int i0 = (blockIdx.x & 31) << 7;     // 128-i block tile
    const int split = blockIdx.y;              // 0..7
    const int wave = tid >> 6, lane = tid & 63;
    const int lo = lane & 15, hi = lane >> 4;
    const int iB = i0 + wave * 32;             // this wave's 32 i-rows

    const short* Kb = Kt + (size_t)b * N_ * 64;
    const short* Vb = Vp + (size_t)b * 64 * N_;

    // Q B-frags for 2 i-quarters (16 VGPRs).
    short8 qf[2][2];
    #pragma unroll
    for (int iq = 0; iq < 2; ++iq) {
        const size_t qbase = ((size_t)(b * N_ + iB + iq * 16 + lo)) * 64;
        qf[iq][0] = *(const short8*)(Qt + qbase + 0 * 32 + hi * 8);
        qf[iq][1] = *(const short8*)(Qt + qbase + 1 * 32 + hi * 8);
    }

    f32x4 o_acc[4][2];  // [ct][iq]  32 regs
    f32x4 l_acc[2];     // 8 regs
    #pragma unroll
    for (int ct = 0; ct < 4; ++ct)
        #pragma unroll
        for (int iq = 0; iq < 2; ++iq) o_acc[ct][iq] = (f32x4){0.f, 0.f, 0.f, 0.f};
    #pragma unroll
    for (int iq = 0; iq < 2; ++iq) l_acc[iq] = (f32x4){0.f, 0.f, 0.f, 0.f};

    short8 ones;
    #pragma unroll
    for (int e = 0; e < 8; ++e) ones[e] = (short)0x3F80;  // bf16 1.0

    constexpr int RS = N_ / (64 * SPLIT);      // 8 iterations of 64 j
    const int jbase = split * (N_ / SPLIT);

    for (int rr = 0; rr < RS; ++rr) {
        const int jw = jbase + rr * 64;        // SAME window for all 4 waves

        // K A-frags: 4 16-j tiles (8 b128; identical across waves -> L1).
        short8 ka[4][2];
        #pragma unroll
        for (int jt = 0; jt < 4; ++jt) {
            const int rbase = (jw + jt * 16 + lo) * 64 + hi * 8;
            ka[jt][0] = *(const short8*)(Kb + rbase);
            ka[jt][1] = *(const short8*)(Kb + rbase + 32);
        }

        // S^T = K Q^T; P = exp2(S^T - M)
        bh4 ph[2][4];
        #pragma unroll
        for (int jt = 0; jt < 4; ++jt) {
            #pragma unroll
            for (int iq = 0; iq < 2; ++iq) {
                f32x4 st = mfma16(ka[jt][0], qf[iq][0], (f32x4){0.f, 0.f, 0.f, 0.f});
                st = mfma16(ka[jt][1], qf[iq][1], st);
                bh4 p;
                #pragma unroll
                for (int r = 0; r < 4; ++r)
                    p[r] = f2bf(__builtin_amdgcn_exp2f(st[r] - MSHIFT));
                ph[iq][jt] = p;
            }
        }
        short8 pf[2][2];  // [iq][jh]: K=32 A-frags per 32-j group
        #pragma unroll
        for (int iq = 0; iq < 2; ++iq)
            #pragma unroll
            for (int jh = 0; jh < 2; ++jh)
                pf[iq][jh] = __builtin_shufflevector(
                    ph[iq][2 * jh], ph[iq][2 * jh + 1], 0, 1, 2, 3, 4, 5, 6, 7);

        // V B-frags (8 b128; identical across waves -> L1), then PV.
        #pragma unroll
        for (int ct = 0; ct < 4; ++ct) {
            const short* vrow = Vb + ((size_t)(ct * 16 + lo)) * N_ + jw + hi * 8;
            const short8 vf0 = *(const short8*)vrow;
            const short8 vf1 = *(const short8*)(vrow + 32);
            #pragma unroll
            for (int iq = 0; iq < 2; ++iq) {
                o_acc[ct][iq] = mfma16(pf[iq][0], vf0, o_acc[ct][iq]);
                o_acc[ct][iq] = mfma16(pf[iq][1], vf1, o_acc[ct][iq]);
            }
        }
        #pragma unroll
        for (int iq = 0; iq < 2; ++iq) {
            l_acc[iq] = mfma16(pf[iq][0], ones, l_acc[iq]);
            l_acc[iq] = mfma16(pf[iq][1], ones, l_acc[iq]);
        }
    }

    // Direct partial store: waves own disjoint i-rows -> no reduction.
    float* myO = pO + (size_t)split * B_ * N_ * C_;
    float* myL = pL + (size_t)split * B_ * N_;
    #pragma unroll
    for (int ct = 0; ct < 4; ++ct)
        #pragma unroll
        for (int iq = 0; iq < 2; ++iq)
            #pragma unroll
            for (int r = 0; r < 4; ++r)
                myO[((size_t)(b * N_ + iB + iq * 16 + hi * 4 + r)) * 64 + ct * 16 + lo] =
                    o_acc[ct][iq][r];
    if (lo == 0)
        #pragma unroll
        for (int iq = 0; iq < 2; ++iq)
            #pragma unroll
            for (int r = 0; r < 4; ++r)
                myL[b * N_ + iB + iq * 16 + hi * 4 + r] = l_acc[iq][r];
}

// 1024 blocks: (b, 16-row i-slice).
__global__ __launch_bounds__(256) void combine_kernel(
    const float* __restrict__ pO, const float* __restrict__ pL,
    const float* __restrict__ x, const float* __restrict__ gamma_p,
    float* __restrict__ out)
{
    __shared__ float tile[16 * 65];  // [i][c] fp32, +1 pad
    const int tid = threadIdx.x;
    const int b  = blockIdx.x >> 8;
    const int i0 = (blockIdx.x & 255) << 4;
    const float g = gamma_p[0];

    {
        const int i_l = tid >> 4;
        const int c0  = (tid & 15) * 4;
        f32x4 acc = {0.f, 0.f, 0.f, 0.f};
        const size_t tbase = ((size_t)(b * N_ + i0 + i_l)) * 64 + c0;
        #pragma unroll
        for (int s = 0; s < SPLIT; ++s) {
            const float4 v = *(const float4*)(pO + (size_t)s * B_ * N_ * C_ + tbase);
            acc[0] += v.x; acc[1] += v.y; acc[2] += v.z; acc[3] += v.w;
        }
        float lsum = 0.f;
        #pragma unroll
        for (int s = 0; s < SPLIT; ++s)
            lsum += pL[(size_t)s * B_ * N_ + b * N_ + i0 + i_l];
        const float sc = g / lsum;
        #pragma unroll
        for (int k = 0; k < 4; ++k)
            tile[i_l * 65 + c0 + k] = acc[k] * sc;
    }
    __syncthreads();

    // Write out[b][c][i0..i0+15] (+x): thread (c = tid>>2, q = tid&3).
    const int c = tid >> 2, q = tid & 3;
    const size_t obase = ((size_t)(b * 64 + c)) * N_ + i0 + q * 4;
    float4 o4;
    o4.x = tile[(q * 4 + 0) * 65 + c];
    o4.y = tile[(q * 4 + 1) * 65 + c];
    o4.z = tile[(q * 4 + 2) * 65 + c];
    o4.w = tile[(q * 4 + 3) * 65 + c];
    const float4 x4 = *(const float4*)(x + obase);
    o4.x += x4.x; o4.y += x4.y; o4.z += x4.z; o4.w += x4.w;
    *(float4*)(out + obase) = o4;
}

extern "C" void kernel_launch(void* const* d_in, const int* in_sizes, int n_in,
                              void* d_out, int out_size, void* d_ws, size_t ws_size,
                              hipStream_t stream) {
    const float* x     = (const float*)d_in[0];
    const float* Wq    = (const float*)d_in[1];
    const float* bq    = (const float*)d_in[2];
    const float* Wk    = (const float*)d_in[3];
    const float* bk    = (const float*)d_in[4];
    const float* Wv    = (const float*)d_in[5];
    const float* bv    = (const float*)d_in[6];
    const float* gamma = (const float*)d_in[7];
    float* out = (float*)d_out;

    // ws: Qt(2MB) Kt(2MB) Vp(2MB) pO(8x4MB fp32) pL(8x64KB fp32) ~= 38.5MB
    short* Qt = (short*)d_ws;
    short* Kt = Qt + (size_t)B_ * N_ * C_;
    short* Vp = Kt + (size_t)B_ * N_ * C_;
    float* pO = (float*)(Vp + (size_t)B_ * N_ * C_);
    float* pL = pO + (size_t)SPLIT * B_ * N_ * C_;

    proj_kernel<<<dim3(B_ * (N_ / 16)), dim3(256), 0, stream>>>(
        x, Wq, bq, Wk, bk, Wv, bv, Qt, Kt, Vp);
    attn_kernel<<<dim3(B_ * (N_ / 128), SPLIT), dim3(256), 0, stream>>>(Qt, Kt, Vp, pO, pL);
    combine_kernel<<<dim3(B_ * (N_ / 16)), dim3(256), 0, stream>>>(pO, pL, x, gamma, out);
}

// Round 15
// 117.423 us; speedup vs baseline: 1.2851x; 1.2851x over previous
//
#include <hip/hip_runtime.h>

// SelfAttentionBlock: B=4, C=64, N=4096, fp32 in/out.
// R15: revert to R13 (best: 118us; R14's shared-j-window doubled per-wave
// VMEM issue and halved MfmaUtil -> 80us). One change: split partials pO
// stored as bf16 (attn WRITE 16.6->8.3MB, combine reads halved). pL fp32.

#define B_ 4
#define C_ 64
#define N_ 4096
#define LDSK 70    // proj LDS stride (bf16)
#define LDSW 18    // proj V-buf stride
#define SPLIT 4
#define MSHIFT 12.0f
#define QSCALE 0.18033688011111773f  // (1/sqrt(64)) * log2(e)

typedef short short8 __attribute__((ext_vector_type(8)));
typedef short bh4 __attribute__((ext_vector_type(4)));
typedef float f32x4 __attribute__((ext_vector_type(4)));

__device__ __forceinline__ short f2bf(float f) {
    __bf16 h = (__bf16)f;
    return __builtin_bit_cast(short, h);
}

__device__ __forceinline__ float bf2f(short h) {
    return __builtin_bit_cast(float, ((unsigned)(unsigned short)h) << 16);
}

__device__ __forceinline__ f32x4 mfma16(short8 a, short8 b, f32x4 c) {
    return __builtin_amdgcn_mfma_f32_16x16x32_bf16(a, b, c, 0, 0, 0);
}

__device__ __forceinline__ short8 loadWfrag(const float* __restrict__ W, int row, int kbase) {
    const float4 f0 = *(const float4*)(W + row * 64 + kbase);
    const float4 f1 = *(const float4*)(W + row * 64 + kbase + 4);
    short8 r;
    r[0] = f2bf(f0.x); r[1] = f2bf(f0.y); r[2] = f2bf(f0.z); r[3] = f2bf(f0.w);
    r[4] = f2bf(f1.x); r[5] = f2bf(f1.y); r[6] = f2bf(f1.z); r[7] = f2bf(f1.w);
    return r;
}

// 1024 blocks: (b, 16-row n-slice). Each wave owns one 16-wide o/c quarter.
// V goes to Vp: within each 32-j group, short position p = hi*8+e holds
// j = (e<4 ? hi*4+e : 16+hi*4+e-4)  -> attn's PV B-frag is one b128.
__global__ __launch_bounds__(256) void proj_kernel(
    const float* __restrict__ x,
    const float* __restrict__ Wq, const float* __restrict__ bq,
    const float* __restrict__ Wk, const float* __restrict__ bk,
    const float* __restrict__ Wv, const float* __restrict__ bv,
    short* __restrict__ Qt, short* __restrict__ Kt, short* __restrict__ Vp)
{
    __shared__ __align__(16) short xT[16 * LDSK];    // [n][c]
    __shared__ __align__(16) short bufQ[16 * LDSK];  // [n][o]
    __shared__ __align__(16) short bufK[16 * LDSK];
    __shared__ __align__(16) short bufV[64 * LDSW];  // [c][n_local]
    const int tid = threadIdx.x;
    const int b  = blockIdx.x >> 8;
    const int n0 = (blockIdx.x & 255) << 4;
    const int w = tid >> 6, lane = tid & 63;
    const int lo = lane & 15, hi = lane >> 4;

    // Stage x^T tile [16n][64c]: thread (c = tid>>2, nq = tid&3) reads float4.
    {
        const int c  = tid >> 2;
        const int nq = tid & 3;
        const float4 v = *(const float4*)(x + ((size_t)(b * C_ + c)) * N_ + n0 + nq * 4);
        xT[(nq * 4 + 0) * LDSK + c] = f2bf(v.x);
        xT[(nq * 4 + 1) * LDSK + c] = f2bf(v.y);
        xT[(nq * 4 + 2) * LDSK + c] = f2bf(v.z);
        xT[(nq * 4 + 3) * LDSK + c] = f2bf(v.w);
    }
    __syncthreads();

    short8 aX[2];
    aX[0] = *(const short8*)&xT[lo * LDSK + 0 * 32 + hi * 8];
    aX[1] = *(const short8*)&xT[lo * LDSK + 1 * 32 + hi * 8];

    // Q,K: D[n][o], o-quarter = w. A = x^T rows, B = W rows (k-contiguous).
    {
        f32x4 acc = {0.f, 0.f, 0.f, 0.f};
        #pragma unroll
        for (int kh = 0; kh < 2; ++kh)
            acc = mfma16(aX[kh], loadWfrag(Wq, w * 16 + lo, kh * 32 + hi * 8), acc);
        const float bs = bq[w * 16 + lo];
        #pragma unroll
        for (int r = 0; r < 4; ++r)
            bufQ[(hi * 4 + r) * LDSK + w * 16 + lo] = f2bf((acc[r] + bs) * QSCALE);
    }
    {
        f32x4 acc = {0.f, 0.f, 0.f, 0.f};
        #pragma unroll
        for (int kh = 0; kh < 2; ++kh)
            acc = mfma16(aX[kh], loadWfrag(Wk, w * 16 + lo, kh * 32 + hi * 8), acc);
        const float bs = bk[w * 16 + lo];
        #pragma unroll
        for (int r = 0; r < 4; ++r)
            bufK[(hi * 4 + r) * LDSK + w * 16 + lo] = f2bf(acc[r] + bs);
    }
    // V: D[o][n], o-quarter = w. A = W rows, B = x^T rows (same frag as aX).
    {
        short8 aV[2];
        aV[0] = loadWfrag(Wv, w * 16 + lo, 0 * 32 + hi * 8);
        aV[1] = loadWfrag(Wv, w * 16 + lo, 1 * 32 + hi * 8);
        f32x4 acc = {0.f, 0.f, 0.f, 0.f};
        #pragma unroll
        for (int kh = 0; kh < 2; ++kh)
            acc = mfma16(aV[kh], aX[kh], acc);
        #pragma unroll
        for (int r = 0; r < 4; ++r) {
            const int o = w * 16 + hi * 4 + r;
            bufV[o * LDSW + lo] = f2bf(acc[r] + bv[o]);
        }
    }
    __syncthreads();

    // Q/K stores: 16x64 shorts contiguous -> 256 threads x 8B.
    {
        const int row = tid >> 4, c4 = (tid & 15) * 4;
        const size_t gbase = ((size_t)(b * N_ + n0 + row)) * 64 + c4;
        *(uint2*)(Qt + gbase) = *(const uint2*)&bufQ[row * LDSK + c4];
        *(uint2*)(Kt + gbase) = *(const uint2*)&bufK[row * LDSK + c4];
    }
    // Vp store: thread (c = tid>>2, p = tid&3) writes n_local p*4..p*4+3.
    {
        const int c = tid >> 2, p = tid & 3;
        const int goff = (n0 & ~31) + p * 8 + ((n0 & 16) ? 4 : 0);
        *(uint2*)(Vp + ((size_t)(b * C_ + c)) * N_ + goff) =
            *(const uint2*)&bufV[c * LDSW + p * 4];
    }
}

// Cross-wave reduction. Waves = (i-group = wave>>1) x (j-window = wave&1);
// waves {2g, 2g+1} hold partials of the same (i,c) cells for group g.
// PASS 0..3 = O ct-quarters (bf16 partials), 4 = l (fp32).
template <int PASS>
__device__ __forceinline__ void red_pass(
    float* __restrict__ red, f32x4 v0, f32x4 v1, f32x4 v2, f32x4 v3,
    int wave, int lane)
{
    __syncthreads();
    const int base = (wave * 64 + lane) * 17;
    #pragma unroll
    for (int r = 0; r < 4; ++r) red[base + 0 * 4 + r] = v0[r];
    #pragma unroll
    for (int r = 0; r < 4; ++r) red[base + 1 * 4 + r] = v1[r];
    #pragma unroll
    for (int r = 0; r < 4; ++r) red[base + 2 * 4 + r] = v2[r];
    #pragma unroll
    for (int r = 0; r < 4; ++r) red[base + 3 * 4 + r] = v3[r];
    __syncthreads();
}

template <int PASS>
__device__ __forceinline__ void red_store(
    const float* __restrict__ red, int tid,
    short* __restrict__ dstO, float* __restrict__ dstL, int b, int i0)
{
    const int L = tid & 63, iq2 = tid >> 6;
    #pragma unroll
    for (int g = 0; g < 2; ++g) {
        float s[4];
        #pragma unroll
        for (int r = 0; r < 4; ++r) {
            float t = 0.f;
            #pragma unroll
            for (int w = 0; w < 2; ++w)
                t += red[((2 * g + w) * 64 + L) * 17 + iq2 * 4 + r];
            s[r] = t;
        }
        const int rowb = i0 + g * 64 + iq2 * 16 + (L >> 4) * 4;
        if (PASS < 4) {
            #pragma unroll
            for (int r = 0; r < 4; ++r)
                dstO[((size_t)(b * N_ + rowb + r)) * 64 + PASS * 16 + (L & 15)] =
                    f2bf(s[r]);
        } else if ((L & 15) == 0) {
            #pragma unroll
            for (int r = 0; r < 4; ++r)
                dstL[b * N_ + rowb + r] = s[r];
        }
    }
}

__global__ __launch_bounds__(256, 2) void attn_kernel(
    const short* __restrict__ Qt, const short* __restrict__ Kt, const short* __restrict__ Vp,
    short* __restrict__ pO, float* __restrict__ pL)
{
    __shared__ float red[4 * 64 * 17];  // 17.4 KB; only LDS in the kernel

    const int tid = threadIdx.x;
    const int b  = blockIdx.x >> 5;            // 32 i0-tiles per batch
    const int i0 = (blockIdx.x & 31) << 7;     // 128-i tiles
    const int split = blockIdx.y;
    const int wave = tid >> 6, lane = tid & 63;
    const int lo = lane & 15, hi = lane >> 4;
    const int igrp = wave >> 1;                // i-group: 0 or 1
    const int jwin = wave & 1;                 // j-window within 64-j tile
    const int iB = i0 + igrp * 64;

    const short* Kb = Kt + (size_t)b * N_ * 64;
    const short* Vb = Vp + (size_t)b * 64 * N_;

    // Q B-frags for this wave's 64 i (4 quarters).
    short8 qf[4][2];
    #pragma unroll
    for (int iq = 0; iq < 4; ++iq) {
        const size_t qbase = ((size_t)(b * N_ + iB + iq * 16 + lo)) * 64;
        qf[iq][0] = *(const short8*)(Qt + qbase + 0 * 32 + hi * 8);
        qf[iq][1] = *(const short8*)(Qt + qbase + 1 * 32 + hi * 8);
    }

    f32x4 o_acc[4][4];  // [ct][iq]
    f32x4 l_acc[4];
    #pragma unroll
    for (int ct = 0; ct < 4; ++ct)
        #pragma unroll
        for (int iq = 0; iq < 4; ++iq) o_acc[ct][iq] = (f32x4){0.f, 0.f, 0.f, 0.f};
    #pragma unroll
    for (int iq = 0; iq < 4; ++iq) l_acc[iq] = (f32x4){0.f, 0.f, 0.f, 0.f};

    short8 ones;
    #pragma unroll
    for (int e = 0; e < 8; ++e) ones[e] = (short)0x3F80;  // bf16 1.0

    constexpr int RS = N_ / (64 * SPLIT);      // 16 iterations of 64 j
    const int jbase = split * RS * 64;
    const int jw0 = jbase + jwin * 32;

    // Software pipeline: ka for iteration 0 loaded in prologue.
    short8 ka[2][2];
    #pragma unroll
    for (int jt2 = 0; jt2 < 2; ++jt2) {
        const int rbase = (jw0 + jt2 * 16 + lo) * 64 + hi * 8;
        ka[jt2][0] = *(const short8*)(Kb + rbase);
        ka[jt2][1] = *(const short8*)(Kb + rbase + 32);
    }

    for (int rr = 0; rr < RS; ++rr) {
        const int jw = jw0 + rr * 64;

        // V B-frags issued at iter top: latency hides under QK + exp2.
        short8 vf[4];
        #pragma unroll
        for (int ct = 0; ct < 4; ++ct)
            vf[ct] = *(const short8*)(Vb + ((size_t)(ct * 16 + lo)) * N_ + jw + hi * 8);

        // S^T = K Q^T; P = exp2(S^T - M)   (ka already in registers)
        bh4 ph[4][2];
        #pragma unroll
        for (int jt2 = 0; jt2 < 2; ++jt2) {
            #pragma unroll
            for (int iq = 0; iq < 4; ++iq) {
                f32x4 st = mfma16(ka[jt2][0], qf[iq][0], (f32x4){0.f, 0.f, 0.f, 0.f});
                st = mfma16(ka[jt2][1], qf[iq][1], st);
                bh4 p;
                #pragma unroll
                for (int r = 0; r < 4; ++r)
                    p[r] = f2bf(__builtin_amdgcn_exp2f(st[r] - MSHIFT));
                ph[iq][jt2] = p;
            }
        }

        // Prefetch next iteration's K fragments: hidden under PV below.
        if (rr + 1 < RS) {
            const int jn = jw + 64;
            #pragma unroll
            for (int jt2 = 0; jt2 < 2; ++jt2) {
                const int rbase = (jn + jt2 * 16 + lo) * 64 + hi * 8;
                ka[jt2][0] = *(const short8*)(Kb + rbase);
                ka[jt2][1] = *(const short8*)(Kb + rbase + 32);
            }
        }

        short8 pf[4];
        #pragma unroll
        for (int iq = 0; iq < 4; ++iq)
            pf[iq] = __builtin_shufflevector(ph[iq][0], ph[iq][1], 0, 1, 2, 3, 4, 5, 6, 7);

        // O += P V^T ; l += P . 1
        #pragma unroll
        for (int ct = 0; ct < 4; ++ct)
            #pragma unroll
            for (int iq = 0; iq < 4; ++iq)
                o_acc[ct][iq] = mfma16(pf[iq], vf[ct], o_acc[ct][iq]);
        #pragma unroll
        for (int iq = 0; iq < 4; ++iq)
            l_acc[iq] = mfma16(pf[iq], ones, l_acc[iq]);
    }

    // Cross-wave reduction (2 waves per i-group), compile-time indexed.
    short* myO = pO + (size_t)split * B_ * N_ * C_;
    float* myL = pL + (size_t)split * B_ * N_;

    red_pass<0>(red, o_acc[0][0], o_acc[0][1], o_acc[0][2], o_acc[0][3], wave, lane);
    red_store<0>(red, tid, myO, myL, b, i0);
    red_pass<1>(red, o_acc[1][0], o_acc[1][1], o_acc[1][2], o_acc[1][3], wave, lane);
    red_store<1>(red, tid, myO, myL, b, i0);
    red_pass<2>(red, o_acc[2][0], o_acc[2][1], o_acc[2][2], o_acc[2][3], wave, lane);
    red_store<2>(red, tid, myO, myL, b, i0);
    red_pass<3>(red, o_acc[3][0], o_acc[3][1], o_acc[3][2], o_acc[3][3], wave, lane);
    red_store<3>(red, tid, myO, myL, b, i0);
    red_pass<4>(red, l_acc[0], l_acc[1], l_acc[2], l_acc[3], wave, lane);
    red_store<4>(red, tid, myO, myL, b, i0);
}

// 1024 blocks: (b, 16-row i-slice). Partials are bf16.
__global__ __launch_bounds__(256) void combine_kernel(
    const short* __restrict__ pO, const float* __restrict__ pL,
    const float* __restrict__ x, const float* __restrict__ gamma_p,
    float* __restrict__ out)
{
    __shared__ float tile[16 * 65];  // [i][c] fp32, +1 pad
    const int tid = threadIdx.x;
    const int b  = blockIdx.x >> 8;
    const int i0 = (blockIdx.x & 255) << 4;
    const float g = gamma_p[0];

    {
        const int i_l = tid >> 4;
        const int c0  = (tid & 15) * 4;
        f32x4 acc = {0.f, 0.f, 0.f, 0.f};
        const size_t tbase = ((size_t)(b * N_ + i0 + i_l)) * 64 + c0;
        #pragma unroll
        for (int s = 0; s < SPLIT; ++s) {
            const bh4 v = *(const bh4*)(pO + (size_t)s * B_ * N_ * C_ + tbase);
            #pragma unroll
            for (int k = 0; k < 4; ++k) acc[k] += bf2f(v[k]);
        }
        float lsum = 0.f;
        #pragma unroll
        for (int s = 0; s < SPLIT; ++s)
            lsum += pL[(size_t)s * B_ * N_ + b * N_ + i0 + i_l];
        const float sc = g / lsum;
        #pragma unroll
        for (int k = 0; k < 4; ++k)
            tile[i_l * 65 + c0 + k] = acc[k] * sc;
    }
    __syncthreads();

    // Write out[b][c][i0..i0+15] (+x): thread (c = tid>>2, q = tid&3).
    const int c = tid >> 2, q = tid & 3;
    const size_t obase = ((size_t)(b * 64 + c)) * N_ + i0 + q * 4;
    float4 o4;
    o4.x = tile[(q * 4 + 0) * 65 + c];
    o4.y = tile[(q * 4 + 1) * 65 + c];
    o4.z = tile[(q * 4 + 2) * 65 + c];
    o4.w = tile[(q * 4 + 3) * 65 + c];
    const float4 x4 = *(const float4*)(x + obase);
    o4.x += x4.x; o4.y += x4.y; o4.z += x4.z; o4.w += x4.w;
    *(float4*)(out + obase) = o4;
}

extern "C" void kernel_launch(void* const* d_in, const int* in_sizes, int n_in,
                              void* d_out, int out_size, void* d_ws, size_t ws_size,
                              hipStream_t stream) {
    const float* x     = (const float*)d_in[0];
    const float* Wq    = (const float*)d_in[1];
    const float* bq    = (const float*)d_in[2];
    const float* Wk    = (const float*)d_in[3];
    const float* bk    = (const float*)d_in[4];
    const float* Wv    = (const float*)d_in[5];
    const float* bv    = (const float*)d_in[6];
    const float* gamma = (const float*)d_in[7];
    float* out = (float*)d_out;

    // ws: Qt(2MB) Kt(2MB) Vp(2MB) pO(4x2MB bf16) pL(4x64KB fp32) ~= 14.3MB
    short* Qt = (short*)d_ws;
    short* Kt = Qt + (size_t)B_ * N_ * C_;
    short* Vp = Kt + (size_t)B_ * N_ * C_;
    short* pO = Vp + (size_t)B_ * N_ * C_;
    float* pL = (float*)(pO + (size_t)SPLIT * B_ * N_ * C_);

    proj_kernel<<<dim3(B_ * (N_ / 16)), dim3(256), 0, stream>>>(
        x, Wq, bq, Wk, bk, Wv, bv, Qt, Kt, Vp);
    attn_kernel<<<dim3(B_ * (N_ / 128), SPLIT), dim3(256), 0, stream>>>(Qt, Kt, Vp, pO, pL);
    combine_kernel<<<dim3(B_ * (N_ / 16)), dim3(256), 0, stream>>>(pO, pL, x, gamma, out);
}